// Round 12
// baseline (133.562 us; speedup 1.0000x reference)
//
#include <hip/hip_runtime.h>
#include <hip/hip_bf16.h>
#include <math.h>

typedef __attribute__((ext_vector_type(8))) short short8;
typedef __attribute__((ext_vector_type(4))) float floatx4;

#define MARGIN_C    0.09f
#define ONE_M_EPS   0.99999f
#define NCLS        64
#define MEMSTRIDE   256

__device__ __forceinline__ unsigned short f2bf(float f) {
    unsigned u = __float_as_uint(f);
    u += 0x7fffu + ((u >> 16) & 1u);
    return (unsigned short)(u >> 16);
}
__device__ __forceinline__ float bf2f(unsigned short v) {
    return __uint_as_float(((unsigned)v) << 16);
}
// order-preserving float<->uint key for atomicMax on floats
__device__ __forceinline__ unsigned fkey(float f) {
    unsigned u = __float_as_uint(f);
    return (u >> 31) ? ~u : (u | 0x80000000u);
}
__device__ __forceinline__ float fdec(unsigned k) {
    return __uint_as_float((k >> 31) ? (k & 0x7fffffffu) : ~k);
}
__device__ __forceinline__ void gld16(const void* g, void* l) {
    __builtin_amdgcn_global_load_lds(
        (const __attribute__((address_space(1))) void*)g,
        (__attribute__((address_space(3))) void*)l, 16, 0, 0);
}

// ---------- fused: fp32->bf16 cvt + stat zeroing + out zeroing + member lists
__global__ __launch_bounds__(256) void cvt_build(const float* __restrict__ in,
                                                 unsigned short* __restrict__ out,
                                                 float* __restrict__ statz,   // negsum+negmax
                                                 const int* __restrict__ labels,
                                                 int* __restrict__ members,
                                                 int* __restrict__ classCount,
                                                 float* __restrict__ loss_out,
                                                 int n4, int nz4, int ncvt, int Bn) {
    __shared__ int cnt;
    const int bid = blockIdx.x;
    const int t = threadIdx.x;
    if (bid < ncvt) {
        int i = bid * 256 + t;
        if (bid == 0 && t == 0) loss_out[0] = 0.0f;
        if (i < nz4) ((float4*)statz)[i] = make_float4(0.f, 0.f, 0.f, 0.f);
        if (i >= n4) return;
        float4 v = ((const float4*)in)[i];
        ushort4 o;
        o.x = f2bf(v.x); o.y = f2bf(v.y); o.z = f2bf(v.z); o.w = f2bf(v.w);
        ((ushort4*)out)[i] = o;
    } else {
        const int c = bid - ncvt;
        if (t == 0) cnt = 0;
        __syncthreads();
        for (int j = t; j < Bn; j += 256) {
            if (labels[j] == c) {
                int p = atomicAdd(&cnt, 1);
                if (p < MEMSTRIDE) members[c * MEMSTRIDE + p] = j;
            }
        }
        __syncthreads();
        if (t == 0) classCount[c] = (cnt < MEMSTRIDE) ? cnt : MEMSTRIDE;
    }
}

// ---------- GEMM (lower-tri 64x64 tiles), SINGLE-WAVE blocks, NO barriers ---
// One 64-lane wave per block computes a 64x64 tile (4x4 MFMA 16x16x32),
// double-buffered gld_lds staging. No __syncthreads in the K-loop: the only
// ordering needed is DMA(s) -> ds_read(s), enforced by an explicit vmcnt(0)
// BEFORE DMA(s+1) is issued (so the wait never covers fresh loads). Latency
// is hidden by TLP: ~16.5KB LDS -> ~9 blocks/CU of independent waves.
__global__ __launch_bounds__(64) void gemm_fused(const unsigned short* __restrict__ fb,
                                                 const int* __restrict__ labels,
                                                 float* __restrict__ negsum,
                                                 unsigned* __restrict__ negmax,
                                                 unsigned short* __restrict__ pairsim,
                                                 int Bn, int Dn) {
    __shared__ __align__(16) unsigned short As[2][2048];   // 8KB  [64][32] dbuf
    __shared__ __align__(16) unsigned short Bs[2][2048];   // 8KB
    __shared__ int Lrow[64], Lcol[64];

    const int bid = blockIdx.x;
    int by = (int)((sqrtf(8.f * (float)bid + 1.f) - 1.f) * 0.5f);
    while ((by + 1) * (by + 2) / 2 <= bid) by++;
    while (by * (by + 1) / 2 > bid) by--;
    const int bx = bid - by * (by + 1) / 2;
    const bool diag = (bx == by);

    const int l = threadIdx.x;           // 0..63
    const int quad = l >> 4, m16 = l & 15;

    Lrow[l] = labels[by * 64 + l];
    Lcol[l] = labels[bx * 64 + l];

    // staging: chunk c (0..3) covers rows c*16 + (l>>2), 16B slot l&3.
    // k-rotation: slot sl of row r holds chunk (sl+r)&3; c*16 % 4 == 0 so
    // kf is chunk-independent.
    const int kf = ((l & 3) + (l >> 2)) & 3;
    const unsigned short* gA = fb + (size_t)(by * 64 + (l >> 2)) * Dn + kf * 8;
    const unsigned short* gB = fb + (size_t)(bx * 64 + (l >> 2)) * Dn + kf * 8;
    const size_t cstep = (size_t)16 * Dn;   // 16 rows per chunk
    const int lb = l * 8;                   // shorts; 16B per lane

    floatx4 acc[4][4];
#pragma unroll
    for (int i = 0; i < 4; i++)
#pragma unroll
        for (int j = 0; j < 4; j++) acc[i][j] = (floatx4){0.f, 0.f, 0.f, 0.f};

    // fragment reads: row i*16+m16 (stride 32 shorts), chunk quad at slot (quad-m16)&3
    const int fragA = m16 * 32 + ((quad - m16) & 3) * 8;
    const int NS = Dn / 32;

    // prologue: DMA(0) -> buf 0
    gld16(gA,             &As[0][lb]);
    gld16(gA + cstep,     &As[0][512 + lb]);
    gld16(gA + 2 * cstep, &As[0][1024 + lb]);
    gld16(gA + 3 * cstep, &As[0][1536 + lb]);
    if (!diag) {
        gld16(gB,             &Bs[0][lb]);
        gld16(gB + cstep,     &Bs[0][512 + lb]);
        gld16(gB + 2 * cstep, &Bs[0][1024 + lb]);
        gld16(gB + 3 * cstep, &Bs[0][1536 + lb]);
    }

    for (int s = 0; s < NS; s++) {
        // wait for DMA(s) only (DMA(s+1) not yet issued)
        asm volatile("s_waitcnt vmcnt(0)" ::: "memory");
        const unsigned short* as_ = &As[s & 1][0];
        const unsigned short* bs_ = diag ? as_ : &Bs[s & 1][0];
        short8 af[4], bfr[4];
#pragma unroll
        for (int i = 0; i < 4; i++) af[i]  = *(const short8*)(as_ + fragA + i * 512);
#pragma unroll
        for (int i = 0; i < 4; i++) bfr[i] = *(const short8*)(bs_ + fragA + i * 512);
        __builtin_amdgcn_sched_barrier(0);   // keep DMA(s+1) below the ds_reads
        if (s + 1 < NS) {
            const int ko = (s + 1) * 32;
            const int nb = (s + 1) & 1;
            gld16(gA + ko,             &As[nb][lb]);
            gld16(gA + cstep + ko,     &As[nb][512 + lb]);
            gld16(gA + 2 * cstep + ko, &As[nb][1024 + lb]);
            gld16(gA + 3 * cstep + ko, &As[nb][1536 + lb]);
            if (!diag) {
                gld16(gB + ko,             &Bs[nb][lb]);
                gld16(gB + cstep + ko,     &Bs[nb][512 + lb]);
                gld16(gB + 2 * cstep + ko, &Bs[nb][1024 + lb]);
                gld16(gB + 3 * cstep + ko, &Bs[nb][1536 + lb]);
            }
        }
#pragma unroll
        for (int i = 0; i < 4; i++)
#pragma unroll
            for (int j = 0; j < 4; j++)
                acc[i][j] = __builtin_amdgcn_mfma_f32_16x16x32_bf16(af[i], bfr[j], acc[i][j], 0, 0, 0);
    }

    // ----- single-pass epilogue (C/D: col = m16 + j*16, row = quad*4+r + i*16)
    const bool offd = !diag;
    int cl[4], gc[4];
#pragma unroll
    for (int j = 0; j < 4; j++) {
        cl[j] = Lcol[j * 16 + m16];
        gc[j] = bx * 64 + j * 16 + m16;
    }

    float nsm[4] = {0.f, 0.f, 0.f, 0.f};
    float nmm[4] = {-INFINITY, -INFINITY, -INFINITY, -INFINITY};

#pragma unroll
    for (int i = 0; i < 4; i++) {
#pragma unroll
        for (int r = 0; r < 4; r++) {
            const int rowl = i * 16 + quad * 4 + r;
            const int rl = Lrow[rowl];
            const int gr = by * 64 + rowl;
            float ns = 0.f, nm = -INFINITY;
#pragma unroll
            for (int j = 0; j < 4; j++) {
                const float s = acc[i][j][r];
                if (cl[j] != rl) {
                    const float e = __expf(40.f * s);
                    ns += e;
                    nm = fmaxf(nm, s);
                    nsm[j] += e;
                    nmm[j] = fmaxf(nmm[j], s);
                } else if ((gr != gc[j]) & (s < ONE_M_EPS)) {
                    const unsigned short v = f2bf(s);
                    pairsim[(size_t)gr * Bn + gc[j]] = v;
                    if (offd) pairsim[(size_t)gc[j] * Bn + gr] = v;
                }
            }
#pragma unroll
            for (int o = 8; o; o >>= 1) {
                ns += __shfl_down(ns, o, 64);
                nm = fmaxf(nm, __shfl_down(nm, o, 64));
            }
            if (m16 == 0) {
                atomicAdd(negsum + gr, ns);
                atomicMax(negmax + gr, fkey(nm));
            }
        }
    }
    if (offd) {   // mirror negative stats: this tile's cols are rows bx*64..
#pragma unroll
        for (int j = 0; j < 4; j++) {
            float v = nsm[j], m = nmm[j];
            v += __shfl_down(v, 16, 64);
            m = fmaxf(m, __shfl_down(m, 16, 64));
            v += __shfl_down(v, 32, 64);
            m = fmaxf(m, __shfl_down(m, 32, 64));
            if (quad == 0) {
                atomicAdd(negsum + gc[j], v);
                atomicMax(negmax + gc[j], fkey(m));
            }
        }
    }
}

// ---------- positives + per-row loss + mean, merged (16 rows/block) ---------
__global__ __launch_bounds__(256) void pos_final(const unsigned short* __restrict__ pairsim,
                                                 const int* __restrict__ labels,
                                                 const int* __restrict__ members,
                                                 const int* __restrict__ classCount,
                                                 const unsigned* __restrict__ negmax,
                                                 const float* __restrict__ negsum,
                                                 float* __restrict__ out, int Bn) {
    __shared__ float part[4];
    const int t = threadIdx.x;
    const int wave = t >> 6, lane = t & 63;
    float wacc = 0.f;
#pragma unroll
    for (int rr = 0; rr < 4; rr++) {
        const int r = blockIdx.x * 16 + wave * 4 + rr;
        if (r >= Bn) break;
        const int lab = labels[r];
        const int n = classCount[lab];
        const int base = lab * MEMSTRIDE;
        const float mx = fdec(negmax[r]);
        const unsigned short* prow = pairsim + (size_t)r * Bn;

        float ps = 0.f, pc = 0.f;
        for (int j = lane; j < n; j += 64) {
            const int m = members[base + j];
            if (m != r) {
                const float s = bf2f(prow[m]);
                if ((s - MARGIN_C) < mx) {
                    ps += __expf(-2.f * s);
                    pc += 1.f;
                }
            }
        }
#pragma unroll
        for (int o = 32; o; o >>= 1) {
            ps += __shfl_down(ps, o, 64);
            pc += __shfl_down(pc, o, 64);
        }
        if (lane == 0) {
            const int nneg = Bn - n;
            if (nneg >= 1 && pc >= 0.5f) {
                float pl = 0.5f * logf((ps + expf(-2.f * 0.501f)) / (pc + 1.f));
                float nl = (1.f / 40.f) * logf((negsum[r] + expf(40.f * 0.531f)) / ((float)nneg + 1.f));
                wacc += logf(5.33f + expf(pl + nl));
            }
        }
    }
    if (lane == 0) part[wave] = wacc;
    __syncthreads();
    if (t == 0) {
        atomicAdd(out, (part[0] + part[1] + part[2] + part[3]) / (float)Bn);
    }
}

extern "C" void kernel_launch(void* const* d_in, const int* in_sizes, int n_in,
                              void* d_out, int out_size, void* d_ws, size_t ws_size,
                              hipStream_t stream) {
    const float* feats = (const float*)d_in[0];
    const int* labels  = (const int*)d_in[1];
    float* out = (float*)d_out;

    const int Bn = in_sizes[1];           // 4096
    const int Dn = in_sizes[0] / Bn;      // 1024

    unsigned short* fb = (unsigned short*)d_ws;                 // bf16 feats [Bn][Dn]
    float* stats    = (float*)(fb + (size_t)Bn * Dn);
    float* negsum   = stats;                                    // [Bn]
    unsigned* negmax = (unsigned*)(stats + Bn);                 // [Bn] keyed
    int* classCount = (int*)(stats + 2 * Bn);                   // [NCLS]
    int* members    = classCount + NCLS;                        // [NCLS][MEMSTRIDE]
    unsigned short* pairsim = (unsigned short*)(members + NCLS * MEMSTRIDE); // [Bn][Bn]

    const int n4   = (Bn * Dn) / 4;
    const int nz4  = (2 * Bn) / 4;        // zero negsum+negmax
    const int ncvt = (n4 + 255) / 256;
    cvt_build<<<ncvt + NCLS, 256, 0, stream>>>(feats, fb, stats, labels,
                                               members, classCount, out,
                                               n4, nz4, ncvt, Bn);

    const int nt = Bn / 64;               // 64
    const int ntri = nt * (nt + 1) / 2;   // 2080
    gemm_fused<<<ntri, 64, 0, stream>>>(fb, labels, negsum, negmax, pairsim, Bn, Dn);

    pos_final<<<(Bn + 15) / 16, 256, 0, stream>>>(pairsim, labels, members, classCount,
                                                  negmax, negsum, out, Bn);
}

// Round 13
// 128.451 us; speedup vs baseline: 1.0398x; 1.0398x over previous
//
#include <hip/hip_runtime.h>
#include <hip/hip_bf16.h>
#include <math.h>

typedef __attribute__((ext_vector_type(8))) short short8;
typedef __attribute__((ext_vector_type(4))) float floatx4;

#define MARGIN_C    0.09f
#define ONE_M_EPS   0.99999f
#define NCLS        64
#define MEMSTRIDE   256

__device__ __forceinline__ unsigned short f2bf(float f) {
    unsigned u = __float_as_uint(f);
    u += 0x7fffu + ((u >> 16) & 1u);
    return (unsigned short)(u >> 16);
}
__device__ __forceinline__ float bf2f(unsigned short v) {
    return __uint_as_float(((unsigned)v) << 16);
}
// order-preserving float<->uint key for atomicMax on floats
__device__ __forceinline__ unsigned fkey(float f) {
    unsigned u = __float_as_uint(f);
    return (u >> 31) ? ~u : (u | 0x80000000u);
}
__device__ __forceinline__ float fdec(unsigned k) {
    return __uint_as_float((k >> 31) ? (k & 0x7fffffffu) : ~k);
}
__device__ __forceinline__ void gld16(const void* g, void* l) {
    __builtin_amdgcn_global_load_lds(
        (const __attribute__((address_space(1))) void*)g,
        (__attribute__((address_space(3))) void*)l, 16, 0, 0);
}

// ---------- fused: fp32->bf16 cvt + stat zeroing + out zeroing + member lists
__global__ __launch_bounds__(256) void cvt_build(const float* __restrict__ in,
                                                 unsigned short* __restrict__ out,
                                                 float* __restrict__ statz,   // negsum+negmax
                                                 const int* __restrict__ labels,
                                                 int* __restrict__ members,
                                                 int* __restrict__ classCount,
                                                 float* __restrict__ loss_out,
                                                 int n4, int nz4, int ncvt, int Bn) {
    __shared__ int cnt;
    const int bid = blockIdx.x;
    const int t = threadIdx.x;
    if (bid < ncvt) {
        int i = bid * 256 + t;
        if (bid == 0 && t == 0) loss_out[0] = 0.0f;
        if (i < nz4) ((float4*)statz)[i] = make_float4(0.f, 0.f, 0.f, 0.f);
        if (i >= n4) return;
        float4 v = ((const float4*)in)[i];
        ushort4 o;
        o.x = f2bf(v.x); o.y = f2bf(v.y); o.z = f2bf(v.z); o.w = f2bf(v.w);
        ((ushort4*)out)[i] = o;
    } else {
        const int c = bid - ncvt;
        if (t == 0) cnt = 0;
        __syncthreads();
        for (int j = t; j < Bn; j += 256) {
            if (labels[j] == c) {
                int p = atomicAdd(&cnt, 1);
                if (p < MEMSTRIDE) members[c * MEMSTRIDE + p] = j;
            }
        }
        __syncthreads();
        if (t == 0) classCount[c] = (cnt < MEMSTRIDE) ? cnt : MEMSTRIDE;
    }
}

// ---------- GEMM (lower-tri tiles) + fused neg stats + pos scatter ----------
// 128x128 tile, BK=64 (16 stages), double-buffered global_load_lds (R10's
// winning barrier discipline + R8's verified BK=64 LDS geometry, 0 conflicts).
// Inter-barrier interval doubles (32 MFMA + 16 ds_read) -> the vmcnt(0) drain
// at __syncthreads comes ~600-800cyc after DMA issue, covering L2/L3 latency.
// Grid = exactly 512 blocks: bids 0..15 each run TWO diagonal tiles (diag
// skips B staging ~ half cost), bids 16..511 one off-diag tile each -> every
// CU gets exactly 2 resident blocks, no 528-on-512 straggler tail.
__global__ __launch_bounds__(256, 2) void gemm_fused(const unsigned short* __restrict__ fb,
                                                     const int* __restrict__ labels,
                                                     float* __restrict__ negsum,
                                                     unsigned* __restrict__ negmax,
                                                     unsigned short* __restrict__ pairsim,
                                                     int Bn, int Dn) {
    __shared__ __align__(16) unsigned short As[2][8192];   // 32KB  [128][64] dbuf
    __shared__ __align__(16) unsigned short Bs[2][8192];   // 32KB
    __shared__ int Lrow[128], Lcol[128];

    const int bid = blockIdx.x;
    int by, bx, by1 = 0, bx1 = 0, ntl;
    if (bid < 16) {               // two diagonal tiles
        ntl = 2;
        by = bx = bid * 2;
        by1 = bx1 = bid * 2 + 1;
    } else {                      // one off-diagonal tile (bx < by)
        ntl = 1;
        const int m = bid - 16;
        by = (int)((1.f + sqrtf(8.f * (float)m + 1.f)) * 0.5f);
        while (by * (by - 1) / 2 > m) by--;
        while ((by + 1) * by / 2 <= m) by++;
        bx = m - by * (by - 1) / 2;
    }

    const int t = threadIdx.x;
    const int wave = t >> 6, lane = t & 63;
    const int wr = wave >> 1, wc = wave & 1;
    const int quad = lane >> 4, m16 = lane & 15;

    // staging geometry (R8-verified): granule q covers rows q*32 + (t>>3),
    // 16B slot t&7; k-rotation kf = ((t&7) + (t>>3)) & 7 (shared across q).
    const int r0 = t >> 3, kf = (((t & 7) + r0) & 7);
    const size_t rstep = (size_t)32 * Dn;
    const int lb = t * 8;   // shorts (16B per thread per granule)

    // fragment reads: row stride 64 shorts; k-chunk x = s2*4+quad at slot (x-m16)&7
    const int fragA = (wr * 64 + m16) * 64;
    const int fragB = (wc * 64 + m16) * 64;
    const int sK0 = (quad - m16) & 7;
    const int sK1 = (quad + 4 - m16) & 7;
    const int NS = Dn / 64;   // 16 stages

    for (int tt = 0; ; tt++) {
        const bool diag = (bx == by);
        __syncthreads();   // prior tile's epilogue label-reads done
        if (t < 128) Lrow[t] = labels[by * 128 + t];
        else         Lcol[t - 128] = labels[bx * 128 + (t - 128)];

        const unsigned short* gA = fb + (size_t)(by * 128 + r0) * Dn + kf * 8;
        const unsigned short* gB = fb + (size_t)(bx * 128 + r0) * Dn + kf * 8;

        floatx4 acc[4][4];
#pragma unroll
        for (int i = 0; i < 4; i++)
#pragma unroll
            for (int j = 0; j < 4; j++) acc[i][j] = (floatx4){0.f, 0.f, 0.f, 0.f};

        // prologue: DMA(0) -> buf 0
        gld16(gA,             &As[0][lb]);
        gld16(gA + rstep,     &As[0][2048 + lb]);
        gld16(gA + 2 * rstep, &As[0][4096 + lb]);
        gld16(gA + 3 * rstep, &As[0][6144 + lb]);
        if (!diag) {
            gld16(gB,             &Bs[0][lb]);
            gld16(gB + rstep,     &Bs[0][2048 + lb]);
            gld16(gB + 2 * rstep, &Bs[0][4096 + lb]);
            gld16(gB + 3 * rstep, &Bs[0][6144 + lb]);
        }
        __syncthreads();   // drains DMA(0) + labels visible

        for (int s = 0; s < NS; s++) {
            if (s + 1 < NS) {
                const int ko = (s + 1) * 64;
                const int nb = (s + 1) & 1;
                unsigned short* aw = &As[nb][0];
                gld16(gA + ko,             aw + lb);
                gld16(gA + rstep + ko,     aw + 2048 + lb);
                gld16(gA + 2 * rstep + ko, aw + 4096 + lb);
                gld16(gA + 3 * rstep + ko, aw + 6144 + lb);
                if (!diag) {
                    unsigned short* bw = &Bs[nb][0];
                    gld16(gB + ko,             bw + lb);
                    gld16(gB + rstep + ko,     bw + 2048 + lb);
                    gld16(gB + 2 * rstep + ko, bw + 4096 + lb);
                    gld16(gB + 3 * rstep + ko, bw + 6144 + lb);
                }
            }
            __builtin_amdgcn_sched_barrier(0);   // pin DMA issue before compute

            const unsigned short* as_ = &As[s & 1][0];
            const unsigned short* bs_ = diag ? as_ : &Bs[s & 1][0];
            short8 af[4], bfr[4];
            // k-step 0
#pragma unroll
            for (int i = 0; i < 4; i++) af[i]  = *(const short8*)(as_ + fragA + i * 1024 + sK0 * 8);
#pragma unroll
            for (int i = 0; i < 4; i++) bfr[i] = *(const short8*)(bs_ + fragB + i * 1024 + sK0 * 8);
#pragma unroll
            for (int i = 0; i < 4; i++)
#pragma unroll
                for (int j = 0; j < 4; j++)
                    acc[i][j] = __builtin_amdgcn_mfma_f32_16x16x32_bf16(af[i], bfr[j], acc[i][j], 0, 0, 0);
            // k-step 1
#pragma unroll
            for (int i = 0; i < 4; i++) af[i]  = *(const short8*)(as_ + fragA + i * 1024 + sK1 * 8);
#pragma unroll
            for (int i = 0; i < 4; i++) bfr[i] = *(const short8*)(bs_ + fragB + i * 1024 + sK1 * 8);
#pragma unroll
            for (int i = 0; i < 4; i++)
#pragma unroll
                for (int j = 0; j < 4; j++)
                    acc[i][j] = __builtin_amdgcn_mfma_f32_16x16x32_bf16(af[i], bfr[j], acc[i][j], 0, 0, 0);

            __syncthreads();   // drains DMA(s+1): issued one full stage ago
        }

        // ----- single-pass epilogue (C/D: col = m16+j*16, row = quad*4+r+i*16)
        const bool offd = !diag;
        int cl[4], gc[4];
#pragma unroll
        for (int j = 0; j < 4; j++) {
            cl[j] = Lcol[wc * 64 + j * 16 + m16];
            gc[j] = bx * 128 + wc * 64 + j * 16 + m16;
        }

        float nsm[4] = {0.f, 0.f, 0.f, 0.f};
        float nmm[4] = {-INFINITY, -INFINITY, -INFINITY, -INFINITY};

#pragma unroll
        for (int i = 0; i < 4; i++) {
#pragma unroll
            for (int r = 0; r < 4; r++) {
                const int rowl = wr * 64 + i * 16 + quad * 4 + r;
                const int rl = Lrow[rowl];
                const int gr = by * 128 + rowl;
                float ns = 0.f, nm = -INFINITY;
#pragma unroll
                for (int j = 0; j < 4; j++) {
                    const float s = acc[i][j][r];
                    if (cl[j] != rl) {
                        const float e = __expf(40.f * s);
                        ns += e;
                        nm = fmaxf(nm, s);
                        nsm[j] += e;
                        nmm[j] = fmaxf(nmm[j], s);
                    } else if ((gr != gc[j]) & (s < ONE_M_EPS)) {
                        const unsigned short v = f2bf(s);
                        pairsim[(size_t)gr * Bn + gc[j]] = v;
                        if (offd) pairsim[(size_t)gc[j] * Bn + gr] = v;
                    }
                }
#pragma unroll
                for (int o = 8; o; o >>= 1) {
                    ns += __shfl_down(ns, o, 64);
                    nm = fmaxf(nm, __shfl_down(nm, o, 64));
                }
                if (m16 == 0) {
                    atomicAdd(negsum + gr, ns);
                    atomicMax(negmax + gr, fkey(nm));
                }
            }
        }
        if (offd) {   // mirror negative stats: this tile's cols are rows bx*128..
#pragma unroll
            for (int j = 0; j < 4; j++) {
                float v = nsm[j], m = nmm[j];
                v += __shfl_down(v, 16, 64);
                m = fmaxf(m, __shfl_down(m, 16, 64));
                v += __shfl_down(v, 32, 64);
                m = fmaxf(m, __shfl_down(m, 32, 64));
                if (quad == 0) {
                    atomicAdd(negsum + gc[j], v);
                    atomicMax(negmax + gc[j], fkey(m));
                }
            }
        }

        if (tt + 1 >= ntl) break;
        by = by1; bx = bx1;
    }
}

// ---------- positives + per-row loss + mean, merged (16 rows/block) ---------
__global__ __launch_bounds__(256) void pos_final(const unsigned short* __restrict__ pairsim,
                                                 const int* __restrict__ labels,
                                                 const int* __restrict__ members,
                                                 const int* __restrict__ classCount,
                                                 const unsigned* __restrict__ negmax,
                                                 const float* __restrict__ negsum,
                                                 float* __restrict__ out, int Bn) {
    __shared__ float part[4];
    const int t = threadIdx.x;
    const int wave = t >> 6, lane = t & 63;
    float wacc = 0.f;
#pragma unroll
    for (int rr = 0; rr < 4; rr++) {
        const int r = blockIdx.x * 16 + wave * 4 + rr;
        if (r >= Bn) break;
        const int lab = labels[r];
        const int n = classCount[lab];
        const int base = lab * MEMSTRIDE;
        const float mx = fdec(negmax[r]);
        const unsigned short* prow = pairsim + (size_t)r * Bn;

        float ps = 0.f, pc = 0.f;
        for (int j = lane; j < n; j += 64) {
            const int m = members[base + j];
            if (m != r) {
                const float s = bf2f(prow[m]);
                if ((s - MARGIN_C) < mx) {
                    ps += __expf(-2.f * s);
                    pc += 1.f;
                }
            }
        }
#pragma unroll
        for (int o = 32; o; o >>= 1) {
            ps += __shfl_down(ps, o, 64);
            pc += __shfl_down(pc, o, 64);
        }
        if (lane == 0) {
            const int nneg = Bn - n;
            if (nneg >= 1 && pc >= 0.5f) {
                float pl = 0.5f * logf((ps + expf(-2.f * 0.501f)) / (pc + 1.f));
                float nl = (1.f / 40.f) * logf((negsum[r] + expf(40.f * 0.531f)) / ((float)nneg + 1.f));
                wacc += logf(5.33f + expf(pl + nl));
            }
        }
    }
    if (lane == 0) part[wave] = wacc;
    __syncthreads();
    if (t == 0) {
        atomicAdd(out, (part[0] + part[1] + part[2] + part[3]) / (float)Bn);
    }
}

extern "C" void kernel_launch(void* const* d_in, const int* in_sizes, int n_in,
                              void* d_out, int out_size, void* d_ws, size_t ws_size,
                              hipStream_t stream) {
    const float* feats = (const float*)d_in[0];
    const int* labels  = (const int*)d_in[1];
    float* out = (float*)d_out;

    const int Bn = in_sizes[1];           // 4096
    const int Dn = in_sizes[0] / Bn;      // 1024

    unsigned short* fb = (unsigned short*)d_ws;                 // bf16 feats [Bn][Dn]
    float* stats    = (float*)(fb + (size_t)Bn * Dn);
    float* negsum   = stats;                                    // [Bn]
    unsigned* negmax = (unsigned*)(stats + Bn);                 // [Bn] keyed
    int* classCount = (int*)(stats + 2 * Bn);                   // [NCLS]
    int* members    = classCount + NCLS;                        // [NCLS][MEMSTRIDE]
    unsigned short* pairsim = (unsigned short*)(members + NCLS * MEMSTRIDE); // [Bn][Bn]

    const int n4   = (Bn * Dn) / 4;
    const int nz4  = (2 * Bn) / 4;        // zero negsum+negmax
    const int ncvt = (n4 + 255) / 256;
    cvt_build<<<ncvt + NCLS, 256, 0, stream>>>(feats, fb, stats, labels,
                                               members, classCount, out,
                                               n4, nz4, ncvt, Bn);

    // grid 512: 16 diag-pair blocks first, then 496 off-diag blocks
    const int nt = Bn / 128;              // 32
    const int ngrid = 16 + nt * (nt - 1) / 2;   // 512
    gemm_fused<<<ngrid, 256, 0, stream>>>(fb, labels, negsum, negmax, pairsim, Bn, Dn);

    pos_final<<<(Bn + 15) / 16, 256, 0, stream>>>(pairsim, labels, members, classCount,
                                                  negmax, negsum, out, Bn);
}

// Round 14
// 113.592 us; speedup vs baseline: 1.1758x; 1.1308x over previous
//
#include <hip/hip_runtime.h>
#include <hip/hip_bf16.h>
#include <math.h>

typedef __attribute__((ext_vector_type(4))) float floatx4;

#define MARGIN_C    0.09f
#define ONE_M_EPS   0.99999f
#define NCLS        64
#define MEMSTRIDE   256

__device__ __forceinline__ unsigned short f2bf(float f) {
    unsigned u = __float_as_uint(f);
    u += 0x7fffu + ((u >> 16) & 1u);
    return (unsigned short)(u >> 16);
}
__device__ __forceinline__ float bf2f(unsigned short v) {
    return __uint_as_float(((unsigned)v) << 16);
}
// order-preserving float<->uint key for atomicMax on floats
__device__ __forceinline__ unsigned fkey(float f) {
    unsigned u = __float_as_uint(f);
    return (u >> 31) ? ~u : (u | 0x80000000u);
}
__device__ __forceinline__ float fdec(unsigned k) {
    return __uint_as_float((k >> 31) ? (k & 0x7fffffffu) : ~k);
}
__device__ __forceinline__ void gld16(const void* g, void* l) {
    __builtin_amdgcn_global_load_lds(
        (const __attribute__((address_space(1))) void*)g,
        (__attribute__((address_space(3))) void*)l, 16, 0, 0);
}

// ---------- fused: fp32->fp8 cvt + stat zeroing + out zeroing + member lists
__global__ __launch_bounds__(256) void cvt_build(const float* __restrict__ in,
                                                 unsigned* __restrict__ out8,   // 4 fp8 per uint
                                                 float* __restrict__ statz,     // negsum+negmax
                                                 const int* __restrict__ labels,
                                                 int* __restrict__ members,
                                                 int* __restrict__ classCount,
                                                 float* __restrict__ loss_out,
                                                 int n4, int nz4, int ncvt, int Bn) {
    __shared__ int cnt;
    const int bid = blockIdx.x;
    const int t = threadIdx.x;
    if (bid < ncvt) {
        int i = bid * 256 + t;
        if (bid == 0 && t == 0) loss_out[0] = 0.0f;
        if (i < nz4) ((float4*)statz)[i] = make_float4(0.f, 0.f, 0.f, 0.f);
        if (i >= n4) return;
        float4 v = ((const float4*)in)[i];
        int w = __builtin_amdgcn_cvt_pk_fp8_f32(v.x, v.y, 0, false);   // bytes 0,1
        w = __builtin_amdgcn_cvt_pk_fp8_f32(v.z, v.w, w, true);        // bytes 2,3
        out8[i] = (unsigned)w;
    } else {
        const int c = bid - ncvt;
        if (t == 0) cnt = 0;
        __syncthreads();
        for (int j = t; j < Bn; j += 256) {
            if (labels[j] == c) {
                int p = atomicAdd(&cnt, 1);
                if (p < MEMSTRIDE) members[c * MEMSTRIDE + p] = j;
            }
        }
        __syncthreads();
        if (t == 0) classCount[c] = (cnt < MEMSTRIDE) ? cnt : MEMSTRIDE;
    }
}

// ---------- GEMM (lower-tri tiles), FP8 e4m3, fused epilogue ----------------
// 128x128 tile, stage = 64 fp8 elements = 64B/row: SAME bytes/DMAs per stage
// as R10's bf16 BK=32 (4 gld16/thread), but 2x MFMA per stage (2 k-steps of
// mfma_f32_16x16x32_fp8_fp8) -> drains halve (16 vs 32). LDS 32KB (2 bufs
// x 8KB x A/B), same occupancy as R10. XOR swizzle (hc ^ (row&6)) applied on
// the GLOBAL fetch side (gld_lds forces linear LDS placement): fragment
// ds_read_b64 hits only 2-way bank aliasing (free).
__global__ __launch_bounds__(256, 2) void gemm_fused(const unsigned char* __restrict__ fb8,
                                                     const int* __restrict__ labels,
                                                     float* __restrict__ negsum,
                                                     unsigned* __restrict__ negmax,
                                                     unsigned short* __restrict__ pairsim,
                                                     int Bn, int Dn) {
    __shared__ __align__(16) unsigned char As[2][8192];   // [128 rows][64B] dbuf
    __shared__ __align__(16) unsigned char Bs[2][8192];
    __shared__ int Lrow[128], Lcol[128];

    const int bid = blockIdx.x;
    int by = (int)((sqrtf(8.f * (float)bid + 1.f) - 1.f) * 0.5f);
    while ((by + 1) * (by + 2) / 2 <= bid) by++;
    while (by * (by + 1) / 2 > bid) by--;
    const int bx = bid - by * (by + 1) / 2;
    const bool diag = (bx == by);

    const int t = threadIdx.x;
    const int wave = t >> 6, lane = t & 63;
    const int wr = wave >> 1, wc = wave & 1;
    const int quad = lane >> 4, m16 = lane & 15;

    if (t < 128) Lrow[t] = labels[by * 128 + t];
    else         Lcol[t - 128] = labels[bx * 128 + (t - 128)];

    // staging: thread t -> rows r=t>>2 and r+64, 16B slot a=t&3.
    // LDS dest linear (t*16); global fetch offset swizzled:
    // gofs = ((2a) ^ (r&6)) * 8  (covers logical half-chunks 2a^m, 2a^m+1)
    const int r = t >> 2, a = t & 3;
    const int gofs = ((2 * a) ^ (r & 6)) * 8;
    const unsigned char* gA0 = fb8 + (size_t)(by * 128 + r) * Dn + gofs;
    const unsigned char* gB0 = fb8 + (size_t)(bx * 128 + r) * Dn + gofs;
    const unsigned char* gA1 = gA0 + (size_t)64 * Dn;
    const unsigned char* gB1 = gB0 + (size_t)64 * Dn;
    const int lb = t * 16;   // bytes

    floatx4 acc[4][4];
#pragma unroll
    for (int i = 0; i < 4; i++)
#pragma unroll
        for (int j = 0; j < 4; j++) acc[i][j] = (floatx4){0.f, 0.f, 0.f, 0.f};

    // fragment reads (ds_read_b64): row stride 64B; logical half-chunk
    // hc = quad + 4*kstep lives at physical (hc ^ (m16&6))*8
    const int fragA = (wr * 64 + m16) * 64;
    const int fragB = (wc * 64 + m16) * 64;
    const int sw = m16 & 6;
    const int sK0 = (quad ^ sw) * 8;
    const int sK1 = ((quad + 4) ^ sw) * 8;

    const int NS = Dn / 64;   // 16 stages

    // prologue: DMA(0) -> buf 0
    gld16(gA0, &As[0][lb]);
    gld16(gA1, &As[0][4096 + lb]);
    if (!diag) {
        gld16(gB0, &Bs[0][lb]);
        gld16(gB1, &Bs[0][4096 + lb]);
    }
    __syncthreads();   // drains DMA(0); labels visible

    for (int s = 0; s < NS; s++) {
        if (s + 1 < NS) {
            const int ko = (s + 1) * 64;
            const int nb = (s + 1) & 1;
            gld16(gA0 + ko, &As[nb][lb]);
            gld16(gA1 + ko, &As[nb][4096 + lb]);
            if (!diag) {
                gld16(gB0 + ko, &Bs[nb][lb]);
                gld16(gB1 + ko, &Bs[nb][4096 + lb]);
            }
        }
        __builtin_amdgcn_sched_barrier(0);   // pin DMA issue before compute

        const unsigned char* as_ = &As[s & 1][0];
        const unsigned char* bs_ = diag ? as_ : &Bs[s & 1][0];
        long af[4], bfr[4];
        // k-step 0
#pragma unroll
        for (int i = 0; i < 4; i++) af[i]  = *(const long*)(as_ + fragA + i * 1024 + sK0);
#pragma unroll
        for (int i = 0; i < 4; i++) bfr[i] = *(const long*)(bs_ + fragB + i * 1024 + sK0);
#pragma unroll
        for (int i = 0; i < 4; i++)
#pragma unroll
            for (int j = 0; j < 4; j++)
                acc[i][j] = __builtin_amdgcn_mfma_f32_16x16x32_fp8_fp8(af[i], bfr[j], acc[i][j], 0, 0, 0);
        // k-step 1
#pragma unroll
        for (int i = 0; i < 4; i++) af[i]  = *(const long*)(as_ + fragA + i * 1024 + sK1);
#pragma unroll
        for (int i = 0; i < 4; i++) bfr[i] = *(const long*)(bs_ + fragB + i * 1024 + sK1);
#pragma unroll
        for (int i = 0; i < 4; i++)
#pragma unroll
            for (int j = 0; j < 4; j++)
                acc[i][j] = __builtin_amdgcn_mfma_f32_16x16x32_fp8_fp8(af[i], bfr[j], acc[i][j], 0, 0, 0);

        __syncthreads();   // drains DMA(s+1): issued one full stage ago
    }

    // ----- single-pass epilogue (C/D: col = m16 + j*16, row = quad*4+r + i*16)
    const bool offd = !diag;
    int cl[4], gc[4];
#pragma unroll
    for (int j = 0; j < 4; j++) {
        cl[j] = Lcol[wc * 64 + j * 16 + m16];
        gc[j] = bx * 128 + wc * 64 + j * 16 + m16;
    }

    float nsm[4] = {0.f, 0.f, 0.f, 0.f};
    float nmm[4] = {-INFINITY, -INFINITY, -INFINITY, -INFINITY};

#pragma unroll
    for (int i = 0; i < 4; i++) {
#pragma unroll
        for (int rr = 0; rr < 4; rr++) {
            const int rowl = wr * 64 + i * 16 + quad * 4 + rr;
            const int rl = Lrow[rowl];
            const int gr = by * 128 + rowl;
            float ns = 0.f, nm = -INFINITY;
#pragma unroll
            for (int j = 0; j < 4; j++) {
                const float s = acc[i][j][rr];
                if (cl[j] != rl) {
                    const float e = __expf(40.f * s);
                    ns += e;
                    nm = fmaxf(nm, s);
                    nsm[j] += e;
                    nmm[j] = fmaxf(nmm[j], s);
                } else if ((gr != gc[j]) & (s < ONE_M_EPS)) {
                    const unsigned short v = f2bf(s);
                    pairsim[(size_t)gr * Bn + gc[j]] = v;
                    if (offd) pairsim[(size_t)gc[j] * Bn + gr] = v;
                }
            }
#pragma unroll
            for (int o = 8; o; o >>= 1) {
                ns += __shfl_down(ns, o, 64);
                nm = fmaxf(nm, __shfl_down(nm, o, 64));
            }
            if (m16 == 0) {
                atomicAdd(negsum + gr, ns);
                atomicMax(negmax + gr, fkey(nm));
            }
        }
    }
    if (offd) {   // mirror negative stats: this tile's cols are rows bx*128..
#pragma unroll
        for (int j = 0; j < 4; j++) {
            float v = nsm[j], m = nmm[j];
            v += __shfl_down(v, 16, 64);
            m = fmaxf(m, __shfl_down(m, 16, 64));
            v += __shfl_down(v, 32, 64);
            m = fmaxf(m, __shfl_down(m, 32, 64));
            if (quad == 0) {
                atomicAdd(negsum + gc[j], v);
                atomicMax(negmax + gc[j], fkey(m));
            }
        }
    }
}

// ---------- positives + per-row loss + mean, merged (16 rows/block) ---------
__global__ __launch_bounds__(256) void pos_final(const unsigned short* __restrict__ pairsim,
                                                 const int* __restrict__ labels,
                                                 const int* __restrict__ members,
                                                 const int* __restrict__ classCount,
                                                 const unsigned* __restrict__ negmax,
                                                 const float* __restrict__ negsum,
                                                 float* __restrict__ out, int Bn) {
    __shared__ float part[4];
    const int t = threadIdx.x;
    const int wave = t >> 6, lane = t & 63;
    float wacc = 0.f;
#pragma unroll
    for (int rr = 0; rr < 4; rr++) {
        const int r = blockIdx.x * 16 + wave * 4 + rr;
        if (r >= Bn) break;
        const int lab = labels[r];
        const int n = classCount[lab];
        const int base = lab * MEMSTRIDE;
        const float mx = fdec(negmax[r]);
        const unsigned short* prow = pairsim + (size_t)r * Bn;

        float ps = 0.f, pc = 0.f;
        for (int j = lane; j < n; j += 64) {
            const int m = members[base + j];
            if (m != r) {
                const float s = bf2f(prow[m]);
                if ((s - MARGIN_C) < mx) {
                    ps += __expf(-2.f * s);
                    pc += 1.f;
                }
            }
        }
#pragma unroll
        for (int o = 32; o; o >>= 1) {
            ps += __shfl_down(ps, o, 64);
            pc += __shfl_down(pc, o, 64);
        }
        if (lane == 0) {
            const int nneg = Bn - n;
            if (nneg >= 1 && pc >= 0.5f) {
                float pl = 0.5f * logf((ps + expf(-2.f * 0.501f)) / (pc + 1.f));
                float nl = (1.f / 40.f) * logf((negsum[r] + expf(40.f * 0.531f)) / ((float)nneg + 1.f));
                wacc += logf(5.33f + expf(pl + nl));
            }
        }
    }
    if (lane == 0) part[wave] = wacc;
    __syncthreads();
    if (t == 0) {
        atomicAdd(out, (part[0] + part[1] + part[2] + part[3]) / (float)Bn);
    }
}

extern "C" void kernel_launch(void* const* d_in, const int* in_sizes, int n_in,
                              void* d_out, int out_size, void* d_ws, size_t ws_size,
                              hipStream_t stream) {
    const float* feats = (const float*)d_in[0];
    const int* labels  = (const int*)d_in[1];
    float* out = (float*)d_out;

    const int Bn = in_sizes[1];           // 4096
    const int Dn = in_sizes[0] / Bn;      // 1024

    unsigned char* fb8 = (unsigned char*)d_ws;                  // fp8 feats [Bn][Dn]
    float* stats    = (float*)(fb8 + (size_t)Bn * Dn);
    float* negsum   = stats;                                    // [Bn]
    unsigned* negmax = (unsigned*)(stats + Bn);                 // [Bn] keyed
    int* classCount = (int*)(stats + 2 * Bn);                   // [NCLS]
    int* members    = classCount + NCLS;                        // [NCLS][MEMSTRIDE]
    unsigned short* pairsim = (unsigned short*)(members + NCLS * MEMSTRIDE); // [Bn][Bn]

    const int n4   = (Bn * Dn) / 4;
    const int nz4  = (2 * Bn) / 4;        // zero negsum+negmax
    const int ncvt = (n4 + 255) / 256;
    cvt_build<<<ncvt + NCLS, 256, 0, stream>>>(feats, (unsigned*)fb8, stats, labels,
                                               members, classCount, out,
                                               n4, nz4, ncvt, Bn);

    const int nt = Bn / 128;
    const int ntri = nt * (nt + 1) / 2;   // 528
    gemm_fused<<<ntri, 256, 0, stream>>>(fb8, labels, negsum, negmax, pairsim, Bn, Dn);

    pos_final<<<(Bn + 15) / 16, 256, 0, stream>>>(pairsim, labels, members, classCount,
                                                  negmax, negsum, out, Bn);
}

// Round 16
// 107.948 us; speedup vs baseline: 1.2373x; 1.0523x over previous
//
#include <hip/hip_runtime.h>
#include <hip/hip_bf16.h>
#include <math.h>

typedef __attribute__((ext_vector_type(4))) float floatx4;

#define MARGIN_C    0.09f
#define ONE_M_EPS   0.99999f
#define NCLS        64
#define MEMSTRIDE   256

__device__ __forceinline__ unsigned short f2bf(float f) {
    unsigned u = __float_as_uint(f);
    u += 0x7fffu + ((u >> 16) & 1u);
    return (unsigned short)(u >> 16);
}
__device__ __forceinline__ float bf2f(unsigned short v) {
    return __uint_as_float(((unsigned)v) << 16);
}
// order-preserving float<->uint key for atomicMax on floats
__device__ __forceinline__ unsigned fkey(float f) {
    unsigned u = __float_as_uint(f);
    return (u >> 31) ? ~u : (u | 0x80000000u);
}
__device__ __forceinline__ float fdec(unsigned k) {
    return __uint_as_float((k >> 31) ? (k & 0x7fffffffu) : ~k);
}
__device__ __forceinline__ void gld16(const void* g, void* l) {
    __builtin_amdgcn_global_load_lds(
        (const __attribute__((address_space(1))) void*)g,
        (__attribute__((address_space(3))) void*)l, 16, 0, 0);
}

// ---------- fused: fp32->fp8 cvt + stat zeroing + out zeroing + member lists
__global__ __launch_bounds__(256) void cvt_build(const float* __restrict__ in,
                                                 unsigned* __restrict__ out8,   // 4 fp8 per uint
                                                 float* __restrict__ statz,     // negsum+negmax
                                                 const int* __restrict__ labels,
                                                 int* __restrict__ members,
                                                 int* __restrict__ classCount,
                                                 float* __restrict__ loss_out,
                                                 int n4, int nz4, int ncvt, int Bn) {
    __shared__ int cnt;
    const int bid = blockIdx.x;
    const int t = threadIdx.x;
    if (bid < ncvt) {
        int i = bid * 256 + t;
        if (bid == 0 && t == 0) loss_out[0] = 0.0f;
        if (i < nz4) ((float4*)statz)[i] = make_float4(0.f, 0.f, 0.f, 0.f);
        if (i >= n4) return;
        float4 v = ((const float4*)in)[i];
        int w = __builtin_amdgcn_cvt_pk_fp8_f32(v.x, v.y, 0, false);   // bytes 0,1
        w = __builtin_amdgcn_cvt_pk_fp8_f32(v.z, v.w, w, true);        // bytes 2,3
        out8[i] = (unsigned)w;
    } else {
        const int c = bid - ncvt;
        if (t == 0) cnt = 0;
        __syncthreads();
        for (int j = t; j < Bn; j += 256) {
            if (labels[j] == c) {
                int p = atomicAdd(&cnt, 1);
                if (p < MEMSTRIDE) members[c * MEMSTRIDE + p] = j;
            }
        }
        __syncthreads();
        if (t == 0) classCount[c] = (cnt < MEMSTRIDE) ? cnt : MEMSTRIDE;
    }
}

// ---------- GEMM, FP8 e4m3, 128x64 tiles (grid 1056 -> ~4 blocks/CU) --------
// R14's winning dbuf gld_lds discipline, but tiles halved so 4 blocks co-reside
// per CU: one block's vmcnt drain overlaps other blocks' MFMA (m114 wave-level
// overlap — the only mechanism that has worked). LDS ~25KB, acc 2x4 (32 VGPR),
// launch_bounds(256,4). Band by (128 rows) x col-tile c64 (64 cols), c64 <=
// 2*by+1: tiles inside the diagonal 128-block compute both orientations
// naturally; mirror only when the tile is strictly left of the diag block.
__global__ __launch_bounds__(256, 4) void gemm_fused(const unsigned char* __restrict__ fb8,
                                                     const int* __restrict__ labels,
                                                     float* __restrict__ negsum,
                                                     unsigned* __restrict__ negmax,
                                                     unsigned short* __restrict__ pairsim,
                                                     int Bn, int Dn) {
    __shared__ __align__(16) unsigned char As[2][8192];   // [128 rows][64B] dbuf
    __shared__ __align__(16) unsigned char Bs[2][4096];   // [64 rows][64B] dbuf
    __shared__ int Lrow[128], Lcol[64];

    // bid -> (by, c64): band by starts at by*(by+1), has 2*by+2 tiles
    const int bid = blockIdx.x;
    int by = (int)(sqrtf((float)bid + 0.25f) - 0.5f);
    while ((by + 1) * (by + 2) <= bid) by++;
    while (by * (by + 1) > bid) by--;
    const int c64 = bid - by * (by + 1);
    const int gcb = c64 * 64;                 // global col base
    const bool mirror = (gcb < by * 128);     // strictly left of diag block

    const int t = threadIdx.x;
    const int wave = t >> 6, lane = t & 63;
    const int quad = lane >> 4, m16 = lane & 15;

    if (t < 128) Lrow[t] = labels[by * 128 + t];
    else if (t < 192) Lcol[t - 128] = labels[gcb + (t - 128)];

    // staging: A rows r=t>>2 and r+64 (slot a=t&3); B rows r (64 rows, 1 granule).
    // Global fetch XOR-swizzled so linear-LDS ds_read_b64 frags are conflict-free.
    const int r = t >> 2, a = t & 3;
    const int gofs = ((2 * a) ^ (r & 6)) * 8;
    const unsigned char* gA0 = fb8 + (size_t)(by * 128 + r) * Dn + gofs;
    const unsigned char* gA1 = gA0 + (size_t)64 * Dn;
    const unsigned char* gB0 = fb8 + (size_t)(gcb + r) * Dn + gofs;
    const int lb = t * 16;   // bytes

    floatx4 acc[2][4];
#pragma unroll
    for (int i = 0; i < 2; i++)
#pragma unroll
        for (int j = 0; j < 4; j++) acc[i][j] = (floatx4){0.f, 0.f, 0.f, 0.f};

    // fragment reads: row stride 64B; logical half-chunk hc = quad + 4*kstep
    // lives at physical (hc ^ (m16&6))*8
    const int fragA = (wave * 32 + m16) * 64;
    const int fragB = m16 * 64;
    const int sw = m16 & 6;
    const int sK0 = (quad ^ sw) * 8;
    const int sK1 = ((quad + 4) ^ sw) * 8;

    const int NS = Dn / 64;   // 16 stages

    // prologue: DMA(0) -> buf 0 (3 gld16/thread)
    gld16(gA0, &As[0][lb]);
    gld16(gA1, &As[0][4096 + lb]);
    gld16(gB0, &Bs[0][lb]);
    __syncthreads();   // drains DMA(0); labels visible

    for (int s = 0; s < NS; s++) {
        if (s + 1 < NS) {
            const int ko = (s + 1) * 64;
            const int nb = (s + 1) & 1;
            gld16(gA0 + ko, &As[nb][lb]);
            gld16(gA1 + ko, &As[nb][4096 + lb]);
            gld16(gB0 + ko, &Bs[nb][lb]);
        }
        __builtin_amdgcn_sched_barrier(0);   // pin DMA issue before compute

        const unsigned char* as_ = &As[s & 1][0];
        const unsigned char* bs_ = &Bs[s & 1][0];
        long af[2], bfr[4];
        // k-step 0
#pragma unroll
        for (int i = 0; i < 2; i++) af[i]  = *(const long*)(as_ + fragA + i * 1024 + sK0);
#pragma unroll
        for (int j = 0; j < 4; j++) bfr[j] = *(const long*)(bs_ + fragB + j * 1024 + sK0);
#pragma unroll
        for (int i = 0; i < 2; i++)
#pragma unroll
            for (int j = 0; j < 4; j++)
                acc[i][j] = __builtin_amdgcn_mfma_f32_16x16x32_fp8_fp8(af[i], bfr[j], acc[i][j], 0, 0, 0);
        // k-step 1
#pragma unroll
        for (int i = 0; i < 2; i++) af[i]  = *(const long*)(as_ + fragA + i * 1024 + sK1);
#pragma unroll
        for (int j = 0; j < 4; j++) bfr[j] = *(const long*)(bs_ + fragB + j * 1024 + sK1);
#pragma unroll
        for (int i = 0; i < 2; i++)
#pragma unroll
            for (int j = 0; j < 4; j++)
                acc[i][j] = __builtin_amdgcn_mfma_f32_16x16x32_fp8_fp8(af[i], bfr[j], acc[i][j], 0, 0, 0);

        __syncthreads();   // drains DMA(s+1): issued one full stage ago
    }

    // ----- single-pass epilogue (C/D: col = m16 + j*16, row = quad*4+rr + i*16)
    int cl[4], gc[4];
#pragma unroll
    for (int j = 0; j < 4; j++) {
        cl[j] = Lcol[j * 16 + m16];
        gc[j] = gcb + j * 16 + m16;
    }

    float nsm[4] = {0.f, 0.f, 0.f, 0.f};
    float nmm[4] = {-INFINITY, -INFINITY, -INFINITY, -INFINITY};

#pragma unroll
    for (int i = 0; i < 2; i++) {
#pragma unroll
        for (int rr = 0; rr < 4; rr++) {
            const int rowl = wave * 32 + i * 16 + quad * 4 + rr;
            const int rl = Lrow[rowl];
            const int gr = by * 128 + rowl;
            float ns = 0.f, nm = -INFINITY;
#pragma unroll
            for (int j = 0; j < 4; j++) {
                const float s = acc[i][j][rr];
                if (cl[j] != rl) {
                    const float e = __expf(40.f * s);
                    ns += e;
                    nm = fmaxf(nm, s);
                    nsm[j] += e;
                    nmm[j] = fmaxf(nmm[j], s);
                } else if ((gr != gc[j]) & (s < ONE_M_EPS)) {
                    const unsigned short v = f2bf(s);
                    pairsim[(size_t)gr * Bn + gc[j]] = v;
                    if (mirror) pairsim[(size_t)gc[j] * Bn + gr] = v;
                }
            }
#pragma unroll
            for (int o = 8; o; o >>= 1) {
                ns += __shfl_down(ns, o, 64);
                nm = fmaxf(nm, __shfl_down(nm, o, 64));
            }
            if (m16 == 0) {
                atomicAdd(negsum + gr, ns);
                atomicMax(negmax + gr, fkey(nm));
            }
        }
    }
    if (mirror) {   // column stats feed rows gcb.. (only for strictly-left tiles)
#pragma unroll
        for (int j = 0; j < 4; j++) {
            float v = nsm[j], m = nmm[j];
            v += __shfl_down(v, 16, 64);
            m = fmaxf(m, __shfl_down(m, 16, 64));
            v += __shfl_down(v, 32, 64);
            m = fmaxf(m, __shfl_down(m, 32, 64));
            if (quad == 0) {
                atomicAdd(negsum + gc[j], v);
                atomicMax(negmax + gc[j], fkey(m));
            }
        }
    }
}

// ---------- positives + per-row loss + mean, merged (16 rows/block) ---------
__global__ __launch_bounds__(256) void pos_final(const unsigned short* __restrict__ pairsim,
                                                 const int* __restrict__ labels,
                                                 const int* __restrict__ members,
                                                 const int* __restrict__ classCount,
                                                 const unsigned* __restrict__ negmax,
                                                 const float* __restrict__ negsum,
                                                 float* __restrict__ out, int Bn) {
    __shared__ float part[4];
    const int t = threadIdx.x;
    const int wave = t >> 6, lane = t & 63;
    float wacc = 0.f;
#pragma unroll
    for (int rr = 0; rr < 4; rr++) {
        const int r = blockIdx.x * 16 + wave * 4 + rr;
        if (r >= Bn) break;
        const int lab = labels[r];
        const int n = classCount[lab];
        const int base = lab * MEMSTRIDE;
        const float mx = fdec(negmax[r]);
        const unsigned short* prow = pairsim + (size_t)r * Bn;

        float ps = 0.f, pc = 0.f;
        for (int j = lane; j < n; j += 64) {
            const int m = members[base + j];
            if (m != r) {
                const float s = bf2f(prow[m]);
                if ((s - MARGIN_C) < mx) {
                    ps += __expf(-2.f * s);
                    pc += 1.f;
                }
            }
        }
#pragma unroll
        for (int o = 32; o; o >>= 1) {
            ps += __shfl_down(ps, o, 64);
            pc += __shfl_down(pc, o, 64);
        }
        if (lane == 0) {
            const int nneg = Bn - n;
            if (nneg >= 1 && pc >= 0.5f) {
                float pl = 0.5f * logf((ps + expf(-2.f * 0.501f)) / (pc + 1.f));
                float nl = (1.f / 40.f) * logf((negsum[r] + expf(40.f * 0.531f)) / ((float)nneg + 1.f));
                wacc += logf(5.33f + expf(pl + nl));
            }
        }
    }
    if (lane == 0) part[wave] = wacc;
    __syncthreads();
    if (t == 0) {
        atomicAdd(out, (part[0] + part[1] + part[2] + part[3]) / (float)Bn);
    }
}

extern "C" void kernel_launch(void* const* d_in, const int* in_sizes, int n_in,
                              void* d_out, int out_size, void* d_ws, size_t ws_size,
                              hipStream_t stream) {
    const float* feats = (const float*)d_in[0];
    const int* labels  = (const int*)d_in[1];
    float* out = (float*)d_out;

    const int Bn = in_sizes[1];           // 4096
    const int Dn = in_sizes[0] / Bn;      // 1024

    unsigned char* fb8 = (unsigned char*)d_ws;                  // fp8 feats [Bn][Dn]
    float* stats    = (float*)(fb8 + (size_t)Bn * Dn);
    float* negsum   = stats;                                    // [Bn]
    unsigned* negmax = (unsigned*)(stats + Bn);                 // [Bn] keyed
    int* classCount = (int*)(stats + 2 * Bn);                   // [NCLS]
    int* members    = classCount + NCLS;                        // [NCLS][MEMSTRIDE]
    unsigned short* pairsim = (unsigned short*)(members + NCLS * MEMSTRIDE); // [Bn][Bn]

    const int n4   = (Bn * Dn) / 4;
    const int nz4  = (2 * Bn) / 4;        // zero negsum+negmax
    const int ncvt = (n4 + 255) / 256;
    cvt_build<<<ncvt + NCLS, 256, 0, stream>>>(feats, (unsigned*)fb8, stats, labels,
                                               members, classCount, out,
                                               n4, nz4, ncvt, Bn);

    const int nt = Bn / 128;              // 32 bands
    const int ngrid = nt * (nt + 1);      // 1056 tiles of 128x64
    gemm_fused<<<ngrid, 256, 0, stream>>>(fb8, labels, negsum, negmax, pairsim, Bn, Dn);

    pos_final<<<(Bn + 15) / 16, 256, 0, stream>>>(pairsim, labels, members, classCount,
                                                  negmax, negsum, out, Bn);
}